// Round 17
// baseline (179.226 us; speedup 1.0000x reference)
//
#include <hip/hip_runtime.h>
#include <hip/hip_bf16.h>

typedef __bf16 bf16_t;
typedef __bf16 bf16x8 __attribute__((ext_vector_type(8)));
typedef __bf16 bf16x4 __attribute__((ext_vector_type(4)));
typedef float f32x4 __attribute__((ext_vector_type(4)));

#define B_ 2
#define L_ 1024
#define D_ 1024
#define H_ 16
#define HD_ 64

// pack 8 fp32 -> bf16x8 (cast fused into GEMM staging; weights never
// round-trip HBM as bf16)
static __device__ __forceinline__ bf16x8 cvt8(const float4 a, const float4 b) {
    bf16x8 o;
    o[0] = (bf16_t)a.x; o[1] = (bf16_t)a.y;
    o[2] = (bf16_t)a.z; o[3] = (bf16_t)a.w;
    o[4] = (bf16_t)b.x; o[5] = (bf16_t)b.y;
    o[6] = (bf16_t)b.z; o[7] = (bf16_t)b.w;
    return o;
}

// ---------------------------------------------------------------------------
// Prep: x-cast (blocks 0..2047) + E shift+cast (2048..2559).
// ---------------------------------------------------------------------------
__global__ __launch_bounds__(256) void prep_kernel(
    const float* __restrict__ x, const float* __restrict__ E,
    bf16_t* __restrict__ xb, bf16_t* __restrict__ Eb) {
    const int bid = blockIdx.x;
    if (bid < 2048) {
        const int i = bid * 256 + threadIdx.x;
        const float4 v = ((const float4*)x)[i];
        bf16x4 o;
        o[0] = (bf16_t)v.x; o[1] = (bf16_t)v.y;
        o[2] = (bf16_t)v.z; o[3] = (bf16_t)v.w;
        ((bf16x4*)xb)[i] = o;
    } else {
        const int idx = (bid - 2048) * 256 + threadIdx.x;
        if (idx < 64) Eb[idx] = (bf16_t)0.f;
        if (idx < 2047 * 64) Eb[64 + idx] = (bf16_t)E[idx];
    }
}

// ---------------------------------------------------------------------------
// QKV GEMM — r4 64x64 config (best measured; larger tiles spill on this
// compiler regardless of launch-bounds). A-side bf16 xb, B-side stages
// fp32 W with cast. q pre-scale = 0.125*log2e.
// ---------------------------------------------------------------------------
__global__ __launch_bounds__(256) void qkv_gemm_kernel(
    const bf16_t* __restrict__ xb,
    const float* __restrict__ Wqf, const float* __restrict__ Wkf,
    const float* __restrict__ Wvf,
    const float* __restrict__ bq, const float* __restrict__ bk2,
    const float* __restrict__ bv2,
    bf16_t* __restrict__ qbh, bf16_t* __restrict__ kbh,
    bf16_t* __restrict__ vtb) {
    constexpr int K = D_;
    __shared__ __align__(16) bf16_t As[64][72];
    __shared__ __align__(16) bf16_t Bs[64][72];

    const int z = blockIdx.z;
    const float* Wf = (z == 0) ? Wqf : (z == 1) ? Wkf : Wvf;
    const float* bias = (z == 0) ? bq : (z == 1) ? bk2 : bv2;
    const float alpha = (z == 0) ? 0.18033688011112043f : 1.0f;

    const int tid = threadIdx.x;
    const int m0 = blockIdx.y * 64;
    const int n0 = blockIdx.x * 64;
    const int wave = tid >> 6;
    const int lane = tid & 63;
    const int wm = (wave >> 1) << 5;
    const int wn = (wave & 1) << 5;
    const int lrow = lane & 15;
    const int quad = lane >> 4;
    const int r0 = tid >> 3;
    const int c8 = (tid & 7) << 3;

    f32x4 acc[2][2] = {};

    uint4 pA0 = *(const uint4*)&xb[(size_t)(m0 + r0) * K + c8];
    uint4 pA1 = *(const uint4*)&xb[(size_t)(m0 + r0 + 32) * K + c8];
    float4 pB0a = *(const float4*)&Wf[(size_t)(n0 + r0) * K + c8];
    float4 pB0b = *(const float4*)&Wf[(size_t)(n0 + r0) * K + c8 + 4];
    float4 pB1a = *(const float4*)&Wf[(size_t)(n0 + r0 + 32) * K + c8];
    float4 pB1b = *(const float4*)&Wf[(size_t)(n0 + r0 + 32) * K + c8 + 4];

    for (int k0 = 0; k0 < K; k0 += 64) {
        *(uint4*)&As[r0][c8] = pA0;
        *(uint4*)&As[r0 + 32][c8] = pA1;
        *(bf16x8*)&Bs[r0][c8] = cvt8(pB0a, pB0b);
        *(bf16x8*)&Bs[r0 + 32][c8] = cvt8(pB1a, pB1b);
        const int kn = (k0 + 64 < K) ? k0 + 64 : k0;
        pA0 = *(const uint4*)&xb[(size_t)(m0 + r0) * K + kn + c8];
        pA1 = *(const uint4*)&xb[(size_t)(m0 + r0 + 32) * K + kn + c8];
        pB0a = *(const float4*)&Wf[(size_t)(n0 + r0) * K + kn + c8];
        pB0b = *(const float4*)&Wf[(size_t)(n0 + r0) * K + kn + c8 + 4];
        pB1a = *(const float4*)&Wf[(size_t)(n0 + r0 + 32) * K + kn + c8];
        pB1b = *(const float4*)&Wf[(size_t)(n0 + r0 + 32) * K + kn + c8 + 4];
        __syncthreads();

#pragma unroll
        for (int kc = 0; kc < 2; ++kc) {
            bf16x8 af[2], bfr[2];
            af[0]  = *(const bf16x8*)&As[wm + lrow][kc * 32 + 8 * quad];
            af[1]  = *(const bf16x8*)&As[wm + 16 + lrow][kc * 32 + 8 * quad];
            bfr[0] = *(const bf16x8*)&Bs[wn + lrow][kc * 32 + 8 * quad];
            bfr[1] = *(const bf16x8*)&Bs[wn + 16 + lrow][kc * 32 + 8 * quad];
#pragma unroll
            for (int t = 0; t < 2; ++t)
#pragma unroll
                for (int u = 0; u < 2; ++u)
                    acc[t][u] = __builtin_amdgcn_mfma_f32_16x16x32_bf16(
                        af[t], bfr[u], acc[t][u], 0, 0, 0);
        }
        __syncthreads();
    }

#pragma unroll
    for (int t = 0; t < 2; ++t) {
#pragma unroll
        for (int u = 0; u < 2; ++u) {
            const int col = n0 + wn + u * 16 + lrow;
            const float bvv = bias[col];
            const int h = col >> 6, d = col & 63;
            if (z < 2) {
                bf16_t* outp = z ? kbh : qbh;
#pragma unroll
                for (int r = 0; r < 4; ++r) {
                    const int row = m0 + wm + t * 16 + quad * 4 + r;
                    const int b = row >> 10, i = row & 1023;
                    outp[((size_t)((b * H_ + h) * L_ + i)) * HD_ + d] =
                        (bf16_t)((acc[t][u][r] + bvv) * alpha);
                }
            } else {
                const int row0 = m0 + wm + t * 16 + quad * 4;
                const int b = row0 >> 10, i = row0 & 1023;
                bf16x4 pk;
#pragma unroll
                for (int r = 0; r < 4; ++r) pk[r] = (bf16_t)(acc[t][u][r] + bvv);
                *(bf16x4*)&vtb[((size_t)((b * H_ + h) * HD_ + d)) * L_ + i] = pk;
            }
        }
    }
}

// ---------------------------------------------------------------------------
// Wo GEMM: 64x64, 4 waves, reg-dbuf; B-side fp32 Wo + cast.
// ---------------------------------------------------------------------------
__global__ __launch_bounds__(256) void out_gemm_kernel(
    const bf16_t* __restrict__ A, const float* __restrict__ Wf,
    const float* __restrict__ bias, float* __restrict__ outF) {
    constexpr int K = D_;
    __shared__ __align__(16) bf16_t As[64][72];
    __shared__ __align__(16) bf16_t Bs[64][72];

    const int tid = threadIdx.x;
    const int m0 = blockIdx.y * 64;
    const int n0 = blockIdx.x * 64;
    const int wave = tid >> 6;
    const int lane = tid & 63;
    const int wm = (wave >> 1) << 5;
    const int wn = (wave & 1) << 5;
    const int lrow = lane & 15;
    const int quad = lane >> 4;
    const int r0 = tid >> 3;
    const int c8 = (tid & 7) << 3;

    f32x4 acc[2][2] = {};

    uint4 pA0 = *(const uint4*)&A[(size_t)(m0 + r0) * K + c8];
    uint4 pA1 = *(const uint4*)&A[(size_t)(m0 + r0 + 32) * K + c8];
    float4 pB0a = *(const float4*)&Wf[(size_t)(n0 + r0) * K + c8];
    float4 pB0b = *(const float4*)&Wf[(size_t)(n0 + r0) * K + c8 + 4];
    float4 pB1a = *(const float4*)&Wf[(size_t)(n0 + r0 + 32) * K + c8];
    float4 pB1b = *(const float4*)&Wf[(size_t)(n0 + r0 + 32) * K + c8 + 4];

    for (int k0 = 0; k0 < K; k0 += 64) {
        *(uint4*)&As[r0][c8] = pA0;
        *(uint4*)&As[r0 + 32][c8] = pA1;
        *(bf16x8*)&Bs[r0][c8] = cvt8(pB0a, pB0b);
        *(bf16x8*)&Bs[r0 + 32][c8] = cvt8(pB1a, pB1b);
        const int kn = (k0 + 64 < K) ? k0 + 64 : k0;
        pA0 = *(const uint4*)&A[(size_t)(m0 + r0) * K + kn + c8];
        pA1 = *(const uint4*)&A[(size_t)(m0 + r0 + 32) * K + kn + c8];
        pB0a = *(const float4*)&Wf[(size_t)(n0 + r0) * K + kn + c8];
        pB0b = *(const float4*)&Wf[(size_t)(n0 + r0) * K + kn + c8 + 4];
        pB1a = *(const float4*)&Wf[(size_t)(n0 + r0 + 32) * K + kn + c8];
        pB1b = *(const float4*)&Wf[(size_t)(n0 + r0 + 32) * K + kn + c8 + 4];
        __syncthreads();

#pragma unroll
        for (int kc = 0; kc < 2; ++kc) {
            bf16x8 af[2], bfr[2];
            af[0]  = *(const bf16x8*)&As[wm + lrow][kc * 32 + 8 * quad];
            af[1]  = *(const bf16x8*)&As[wm + 16 + lrow][kc * 32 + 8 * quad];
            bfr[0] = *(const bf16x8*)&Bs[wn + lrow][kc * 32 + 8 * quad];
            bfr[1] = *(const bf16x8*)&Bs[wn + 16 + lrow][kc * 32 + 8 * quad];
#pragma unroll
            for (int t = 0; t < 2; ++t)
#pragma unroll
                for (int u = 0; u < 2; ++u)
                    acc[t][u] = __builtin_amdgcn_mfma_f32_16x16x32_bf16(
                        af[t], bfr[u], acc[t][u], 0, 0, 0);
        }
        __syncthreads();
    }

#pragma unroll
    for (int t = 0; t < 2; ++t) {
#pragma unroll
        for (int u = 0; u < 2; ++u) {
            const int col = n0 + wn + u * 16 + lrow;
            const float bvv = bias[col];
#pragma unroll
            for (int r = 0; r < 4; ++r) {
                const int row = m0 + wm + t * 16 + quad * 4 + r;
                outF[(size_t)row * D_ + col] = acc[t][u][r] + bvv;
            }
        }
    }
}

// ---------------------------------------------------------------------------
// MFMA flash attention, r28: pre-skewed band (r27, measured 59.8 us,
// VGPR 100) + bias-folded accumulator init.
// The fixed-shift exponent bias (-24) now rides through the QK^T MFMAs by
// initializing the S accumulators to -24 (MFMA's 3rd operand is C-in):
// s = q.k - 24 falls out of existing instructions; the inner loop does
// exp2(s + sk) — 32 fewer v_add per thread per iteration. Pure fp32
// re-association; output math identical.
// Layout/indices unchanged from r27: skT[p'+qrow][qrow] stride 36,
// reader skT[jj+31][qrow] as bf16x4; fixed-shift softmax (no online max);
// XCD-localized swizzle; setprio on PV; rolled t-loop.
// ---------------------------------------------------------------------------
__global__ __launch_bounds__(256) void fattn_kernel(
    const bf16_t* __restrict__ qbh, const bf16_t* __restrict__ kbh,
    const bf16_t* __restrict__ vtb, const bf16_t* __restrict__ Eb,
    bf16_t* __restrict__ ctx) {
    // loop phase : skT[w] = [127][36] bf16 @ w*9216 B (4572 el < 4608);
    //              P tile reuses skT[w] with stride 72 (2304 el < 4608)
    // merge phase: Om[4][32][64] f32 @ 0 | ml[4][32] f32 @ 32768
    __shared__ __align__(16) char smem[36864];
    float (*Om)[32][64] = (float(*)[32][64])smem;
    float (*ml)[32]     = (float(*)[32])(smem + 32768);

    const int tid = threadIdx.x;
    const int w = tid >> 6;
    const int lane = tid & 63;
    const int q4 = lane >> 4;
    const int n = lane & 15;

    // XCD-localized decode: xcd = bid&7 owns bh in [4*xcd, 4*xcd+4)
    const int bid = blockIdx.x;
    const int xcd = bid & 7;
    const int k = bid >> 3;              // 0..127 within XCD
    const int bh = (xcd << 2) | (k >> 5);
    const int b = bh >> 4;
    const int h = bh & 15;
    const int ib = (k & 31) << 5;

    bf16_t* skT = (bf16_t*)smem + (size_t)w * 4608;
    bf16_t* ps = skT;   // aliased: skT dead after skew-add, P stride 72

    // ones B-fragment for the MFMA row-sum trick
    bf16x8 ones;
#pragma unroll
    for (int e = 0; e < 8; ++e) ones[e] = (bf16_t)1.0f;

    bf16x8 aq[2][2];
#pragma unroll
    for (int m = 0; m < 2; ++m) {
        const bf16x8* qrow =
            (const bf16x8*)(qbh + ((size_t)bh * L_ + ib + 16 * m + n) * HD_);
        aq[m][0] = qrow[q4];
        aq[m][1] = qrow[4 + q4];
    }

    const bf16_t* vbase = vtb + (size_t)bh * HD_ * L_;

    f32x4 o[2][4] = {};
    float l_r[2][4] = {};

    for (int t = 0; t < 4; ++t) {
        const int j0 = w * 256 + t * 64;

        // ---- prefetch K fragments ----
        bf16x8 bk[4][2];
#pragma unroll
        for (int u = 0; u < 4; ++u)
#pragma unroll
            for (int kc = 0; kc < 2; ++kc)
                bk[u][kc] = *(const bf16x8*)(kbh +
                    ((size_t)bh * L_ + j0 + 16 * u + n) * HD_ + kc * 32 + 8 * q4);

        // ---- rel: R = Q @ Eband^T, stored PRE-SKEWED skT[p'+qrow][qrow] ----
        const int rbase = j0 - ib + 992;   // Eb row = rbase + p', p' in [0,96)
#pragma unroll
        for (int up = 0; up < 6; ++up) {
            f32x4 rc[2] = {};
#pragma unroll
            for (int kc = 0; kc < 2; ++kc) {
                const bf16x8 be = *(const bf16x8*)(Eb +
                    ((size_t)(rbase + 16 * up + n)) * HD_ + kc * 32 + 8 * q4);
#pragma unroll
                for (int m = 0; m < 2; ++m)
                    rc[m] = __builtin_amdgcn_mfma_f32_16x16x32_bf16(
                        aq[m][kc], be, rc[m], 0, 0, 0);
            }
            // rc[m][r] = q_{16m+4q4+r} . E_{rbase + 16up + n}
            // store row = p' + qrow = 16(up+m) + n + 4q4 + r, col = qrow
#pragma unroll
            for (int m = 0; m < 2; ++m) {
                const int base =
                    (16 * (up + m) + n + 4 * q4) * 36 + 16 * m + 4 * q4;
#pragma unroll
                for (int r = 0; r < 4; ++r)
                    skT[base + 37 * r] = (bf16_t)rc[m][r];
            }
        }

        // ---- S = Q K^T - 24 (bias folded into accumulator init) ----
        f32x4 s[2][4];
#pragma unroll
        for (int m = 0; m < 2; ++m)
#pragma unroll
            for (int u = 0; u < 4; ++u)
#pragma unroll
                for (int r = 0; r < 4; ++r)
                    s[m][u][r] = -24.0f;
#pragma unroll
        for (int u = 0; u < 4; ++u)
#pragma unroll
            for (int kc = 0; kc < 2; ++kc)
#pragma unroll
                for (int m = 0; m < 2; ++m)
                    s[m][u] = __builtin_amdgcn_mfma_f32_16x16x32_bf16(
                        aq[m][kc], bk[u][kc], s[m][u], 0, 0, 0);

        // ---- prefetch V fragments ----
        bf16x8 vf[4][2];
#pragma unroll
        for (int u = 0; u < 4; ++u)
#pragma unroll
            for (int kc = 0; kc < 2; ++kc)
                vf[u][kc] = *(const bf16x8*)(vbase +
                    ((size_t)(16 * u + n)) * L_ + j0 + kc * 32 + 8 * q4);

        // ---- skew add (vector) + fixed-shift exp2: P = 2^(S + sk) ----
#pragma unroll
        for (int m = 0; m < 2; ++m)
#pragma unroll
            for (int u = 0; u < 4; ++u) {
                const bf16x4 sk = *(const bf16x4*)&skT[
                    (size_t)(16 * u + n + 31) * 36 + 16 * m + 4 * q4];
#pragma unroll
                for (int r = 0; r < 4; ++r)
                    s[m][u][r] = __builtin_amdgcn_exp2f(
                        s[m][u][r] + (float)sk[r]);
            }

        // ---- P -> LDS (stride 72), then A-frags ----
#pragma unroll
        for (int m = 0; m < 2; ++m)
#pragma unroll
            for (int u = 0; u < 4; ++u)
#pragma unroll
                for (int r = 0; r < 4; ++r)
                    ps[(size_t)(16 * m + 4 * q4 + r) * 72 + 16 * u + n] =
                        (bf16_t)s[m][u][r];

        bf16x8 pa[2][2];
#pragma unroll
        for (int m = 0; m < 2; ++m) {
            pa[m][0] = *(const bf16x8*)&ps[(size_t)(16 * m + n) * 72 + 8 * q4];
            pa[m][1] = *(const bf16x8*)&ps[(size_t)(16 * m + n) * 72 + 32 + 8 * q4];
        }

        // ---- row-sum via MFMA P @ ones (no rescale needed) ----
#pragma unroll
        for (int m = 0; m < 2; ++m) {
            f32x4 z = {};
            z = __builtin_amdgcn_mfma_f32_16x16x32_bf16(pa[m][0], ones, z, 0, 0, 0);
            z = __builtin_amdgcn_mfma_f32_16x16x32_bf16(pa[m][1], ones, z, 0, 0, 0);
#pragma unroll
            for (int r = 0; r < 4; ++r)
                l_r[m][r] += z[r];
        }

        // ---- O += P V (pure-MFMA cluster; setprio breaks wave lockstep) ----
        __builtin_amdgcn_s_setprio(1);
#pragma unroll
        for (int u = 0; u < 4; ++u)
#pragma unroll
            for (int kc = 0; kc < 2; ++kc)
#pragma unroll
                for (int m = 0; m < 2; ++m)
                    o[m][u] = __builtin_amdgcn_mfma_f32_16x16x32_bf16(
                        pa[m][kc], vf[u][kc], o[m][u], 0, 0, 0);
        __builtin_amdgcn_s_setprio(0);
    }

    // ---- 4-way cross-wave merge (sum-only: no max bookkeeping) ----
    __syncthreads();
#pragma unroll
    for (int m = 0; m < 2; ++m)
#pragma unroll
        for (int u = 0; u < 4; ++u)
#pragma unroll
            for (int r = 0; r < 4; ++r)
                Om[w][16 * m + 4 * q4 + r][16 * u + n] = o[m][u][r];
    if (n == 0) {
#pragma unroll
        for (int m = 0; m < 2; ++m)
#pragma unroll
            for (int r = 0; r < 4; ++r)
                ml[w][16 * m + 4 * q4 + r] = l_r[m][r];
    }
    __syncthreads();

    {
        const int row = tid >> 3;          // 0..31
        const int c0 = (tid & 7) * 8;      // 0..56
        const float inv = 1.f / (ml[0][row] + ml[1][row] +
                                 ml[2][row] + ml[3][row]);
        bf16_t* dst = ctx + ((size_t)(b * L_ + ib + row)) * D_ + h * HD_ + c0;
#pragma unroll
        for (int cc = 0; cc < 8; ++cc) {
            const int col = c0 + cc;
            const float val = (Om[0][row][col] + Om[1][row][col] +
                               Om[2][row][col] + Om[3][row][col]) * inv;
            dst[cc] = (bf16_t)val;
        }
    }
}

// ---------------------------------------------------------------------------
extern "C" void kernel_launch(void* const* d_in, const int* in_sizes, int n_in,
                              void* d_out, int out_size, void* d_ws,
                              size_t ws_size, hipStream_t stream) {
    const float* x   = (const float*)d_in[0];
    const float* Wq  = (const float*)d_in[1];
    const float* bq  = (const float*)d_in[2];
    const float* Wk  = (const float*)d_in[3];
    const float* bk  = (const float*)d_in[4];
    const float* Wv  = (const float*)d_in[5];
    const float* bv  = (const float*)d_in[6];
    const float* Wo  = (const float*)d_in[7];
    const float* bo  = (const float*)d_in[8];
    const float* E   = (const float*)d_in[9];
    float* out = (float*)d_out;   // fp32 per reference

    char* ws = (char*)d_ws;
    const size_t MB = 1024u * 1024u;
    bf16_t* xb   = (bf16_t*)(ws);             // 4 MB
    bf16_t* qbh  = (bf16_t*)(ws + 4 * MB);    // 4 MB (BH,L,64), pre-scaled
    bf16_t* kbh  = (bf16_t*)(ws + 8 * MB);    // 4 MB (BH,L,64)
    bf16_t* vtb  = (bf16_t*)(ws + 12 * MB);   // 4 MB (BH,64,L) transposed
    bf16_t* ctxb = (bf16_t*)(ws + 16 * MB);   // 4 MB (B,L,D)
    bf16_t* Eb   = (bf16_t*)(ws + 20 * MB);   // 0.25 MB (2048x64)

    prep_kernel<<<2560, 256, 0, stream>>>(x, E, xb, Eb);

    dim3 gq(D_ / 64, (B_ * L_) / 64, 3);  // 1536 blocks
    qkv_gemm_kernel<<<gq, 256, 0, stream>>>(xb, Wq, Wk, Wv, bq, bk, bv,
                                            qbh, kbh, vtb);

    fattn_kernel<<<1024, 256, 0, stream>>>(qbh, kbh, vtb, Eb, ctxb);

    dim3 gg(D_ / 64, (B_ * L_) / 64);  // 512 blocks
    out_gemm_kernel<<<gg, 256, 0, stream>>>(ctxb, Wo, bo, out);
}

// Round 18
// 178.830 us; speedup vs baseline: 1.0022x; 1.0022x over previous
//
#include <hip/hip_runtime.h>
#include <hip/hip_bf16.h>

typedef __bf16 bf16_t;
typedef __bf16 bf16x8 __attribute__((ext_vector_type(8)));
typedef __bf16 bf16x4 __attribute__((ext_vector_type(4)));
typedef float f32x4 __attribute__((ext_vector_type(4)));

#define B_ 2
#define L_ 1024
#define D_ 1024
#define H_ 16
#define HD_ 64

// pack 8 fp32 -> bf16x8 (cast fused into GEMM staging; weights never
// round-trip HBM as bf16)
static __device__ __forceinline__ bf16x8 cvt8(const float4 a, const float4 b) {
    bf16x8 o;
    o[0] = (bf16_t)a.x; o[1] = (bf16_t)a.y;
    o[2] = (bf16_t)a.z; o[3] = (bf16_t)a.w;
    o[4] = (bf16_t)b.x; o[5] = (bf16_t)b.y;
    o[6] = (bf16_t)b.z; o[7] = (bf16_t)b.w;
    return o;
}

// ---------------------------------------------------------------------------
// Prep: x-cast (blocks 0..2047) + E shift+cast (2048..2559).
// ---------------------------------------------------------------------------
__global__ __launch_bounds__(256) void prep_kernel(
    const float* __restrict__ x, const float* __restrict__ E,
    bf16_t* __restrict__ xb, bf16_t* __restrict__ Eb) {
    const int bid = blockIdx.x;
    if (bid < 2048) {
        const int i = bid * 256 + threadIdx.x;
        const float4 v = ((const float4*)x)[i];
        bf16x4 o;
        o[0] = (bf16_t)v.x; o[1] = (bf16_t)v.y;
        o[2] = (bf16_t)v.z; o[3] = (bf16_t)v.w;
        ((bf16x4*)xb)[i] = o;
    } else {
        const int idx = (bid - 2048) * 256 + threadIdx.x;
        if (idx < 64) Eb[idx] = (bf16_t)0.f;
        if (idx < 2047 * 64) Eb[64 + idx] = (bf16_t)E[idx];
    }
}

// ---------------------------------------------------------------------------
// QKV GEMM — r4 64x64 config (best measured; larger tiles spill on this
// compiler regardless of launch-bounds). A-side bf16 xb, B-side stages
// fp32 W with cast. q pre-scale = 0.125*log2e.
// ---------------------------------------------------------------------------
__global__ __launch_bounds__(256) void qkv_gemm_kernel(
    const bf16_t* __restrict__ xb,
    const float* __restrict__ Wqf, const float* __restrict__ Wkf,
    const float* __restrict__ Wvf,
    const float* __restrict__ bq, const float* __restrict__ bk2,
    const float* __restrict__ bv2,
    bf16_t* __restrict__ qbh, bf16_t* __restrict__ kbh,
    bf16_t* __restrict__ vtb) {
    constexpr int K = D_;
    __shared__ __align__(16) bf16_t As[64][72];
    __shared__ __align__(16) bf16_t Bs[64][72];

    const int z = blockIdx.z;
    const float* Wf = (z == 0) ? Wqf : (z == 1) ? Wkf : Wvf;
    const float* bias = (z == 0) ? bq : (z == 1) ? bk2 : bv2;
    const float alpha = (z == 0) ? 0.18033688011112043f : 1.0f;

    const int tid = threadIdx.x;
    const int m0 = blockIdx.y * 64;
    const int n0 = blockIdx.x * 64;
    const int wave = tid >> 6;
    const int lane = tid & 63;
    const int wm = (wave >> 1) << 5;
    const int wn = (wave & 1) << 5;
    const int lrow = lane & 15;
    const int quad = lane >> 4;
    const int r0 = tid >> 3;
    const int c8 = (tid & 7) << 3;

    f32x4 acc[2][2] = {};

    uint4 pA0 = *(const uint4*)&xb[(size_t)(m0 + r0) * K + c8];
    uint4 pA1 = *(const uint4*)&xb[(size_t)(m0 + r0 + 32) * K + c8];
    float4 pB0a = *(const float4*)&Wf[(size_t)(n0 + r0) * K + c8];
    float4 pB0b = *(const float4*)&Wf[(size_t)(n0 + r0) * K + c8 + 4];
    float4 pB1a = *(const float4*)&Wf[(size_t)(n0 + r0 + 32) * K + c8];
    float4 pB1b = *(const float4*)&Wf[(size_t)(n0 + r0 + 32) * K + c8 + 4];

    for (int k0 = 0; k0 < K; k0 += 64) {
        *(uint4*)&As[r0][c8] = pA0;
        *(uint4*)&As[r0 + 32][c8] = pA1;
        *(bf16x8*)&Bs[r0][c8] = cvt8(pB0a, pB0b);
        *(bf16x8*)&Bs[r0 + 32][c8] = cvt8(pB1a, pB1b);
        const int kn = (k0 + 64 < K) ? k0 + 64 : k0;
        pA0 = *(const uint4*)&xb[(size_t)(m0 + r0) * K + kn + c8];
        pA1 = *(const uint4*)&xb[(size_t)(m0 + r0 + 32) * K + kn + c8];
        pB0a = *(const float4*)&Wf[(size_t)(n0 + r0) * K + kn + c8];
        pB0b = *(const float4*)&Wf[(size_t)(n0 + r0) * K + kn + c8 + 4];
        pB1a = *(const float4*)&Wf[(size_t)(n0 + r0 + 32) * K + kn + c8];
        pB1b = *(const float4*)&Wf[(size_t)(n0 + r0 + 32) * K + kn + c8 + 4];
        __syncthreads();

#pragma unroll
        for (int kc = 0; kc < 2; ++kc) {
            bf16x8 af[2], bfr[2];
            af[0]  = *(const bf16x8*)&As[wm + lrow][kc * 32 + 8 * quad];
            af[1]  = *(const bf16x8*)&As[wm + 16 + lrow][kc * 32 + 8 * quad];
            bfr[0] = *(const bf16x8*)&Bs[wn + lrow][kc * 32 + 8 * quad];
            bfr[1] = *(const bf16x8*)&Bs[wn + 16 + lrow][kc * 32 + 8 * quad];
#pragma unroll
            for (int t = 0; t < 2; ++t)
#pragma unroll
                for (int u = 0; u < 2; ++u)
                    acc[t][u] = __builtin_amdgcn_mfma_f32_16x16x32_bf16(
                        af[t], bfr[u], acc[t][u], 0, 0, 0);
        }
        __syncthreads();
    }

#pragma unroll
    for (int t = 0; t < 2; ++t) {
#pragma unroll
        for (int u = 0; u < 2; ++u) {
            const int col = n0 + wn + u * 16 + lrow;
            const float bvv = bias[col];
            const int h = col >> 6, d = col & 63;
            if (z < 2) {
                bf16_t* outp = z ? kbh : qbh;
#pragma unroll
                for (int r = 0; r < 4; ++r) {
                    const int row = m0 + wm + t * 16 + quad * 4 + r;
                    const int b = row >> 10, i = row & 1023;
                    outp[((size_t)((b * H_ + h) * L_ + i)) * HD_ + d] =
                        (bf16_t)((acc[t][u][r] + bvv) * alpha);
                }
            } else {
                const int row0 = m0 + wm + t * 16 + quad * 4;
                const int b = row0 >> 10, i = row0 & 1023;
                bf16x4 pk;
#pragma unroll
                for (int r = 0; r < 4; ++r) pk[r] = (bf16_t)(acc[t][u][r] + bvv);
                *(bf16x4*)&vtb[((size_t)((b * H_ + h) * HD_ + d)) * L_ + i] = pk;
            }
        }
    }
}

// ---------------------------------------------------------------------------
// Wo GEMM: 64x64, 4 waves, reg-dbuf; B-side fp32 Wo + cast.
// ---------------------------------------------------------------------------
__global__ __launch_bounds__(256) void out_gemm_kernel(
    const bf16_t* __restrict__ A, const float* __restrict__ Wf,
    const float* __restrict__ bias, float* __restrict__ outF) {
    constexpr int K = D_;
    __shared__ __align__(16) bf16_t As[64][72];
    __shared__ __align__(16) bf16_t Bs[64][72];

    const int tid = threadIdx.x;
    const int m0 = blockIdx.y * 64;
    const int n0 = blockIdx.x * 64;
    const int wave = tid >> 6;
    const int lane = tid & 63;
    const int wm = (wave >> 1) << 5;
    const int wn = (wave & 1) << 5;
    const int lrow = lane & 15;
    const int quad = lane >> 4;
    const int r0 = tid >> 3;
    const int c8 = (tid & 7) << 3;

    f32x4 acc[2][2] = {};

    uint4 pA0 = *(const uint4*)&A[(size_t)(m0 + r0) * K + c8];
    uint4 pA1 = *(const uint4*)&A[(size_t)(m0 + r0 + 32) * K + c8];
    float4 pB0a = *(const float4*)&Wf[(size_t)(n0 + r0) * K + c8];
    float4 pB0b = *(const float4*)&Wf[(size_t)(n0 + r0) * K + c8 + 4];
    float4 pB1a = *(const float4*)&Wf[(size_t)(n0 + r0 + 32) * K + c8];
    float4 pB1b = *(const float4*)&Wf[(size_t)(n0 + r0 + 32) * K + c8 + 4];

    for (int k0 = 0; k0 < K; k0 += 64) {
        *(uint4*)&As[r0][c8] = pA0;
        *(uint4*)&As[r0 + 32][c8] = pA1;
        *(bf16x8*)&Bs[r0][c8] = cvt8(pB0a, pB0b);
        *(bf16x8*)&Bs[r0 + 32][c8] = cvt8(pB1a, pB1b);
        const int kn = (k0 + 64 < K) ? k0 + 64 : k0;
        pA0 = *(const uint4*)&A[(size_t)(m0 + r0) * K + kn + c8];
        pA1 = *(const uint4*)&A[(size_t)(m0 + r0 + 32) * K + kn + c8];
        pB0a = *(const float4*)&Wf[(size_t)(n0 + r0) * K + kn + c8];
        pB0b = *(const float4*)&Wf[(size_t)(n0 + r0) * K + kn + c8 + 4];
        pB1a = *(const float4*)&Wf[(size_t)(n0 + r0 + 32) * K + kn + c8];
        pB1b = *(const float4*)&Wf[(size_t)(n0 + r0 + 32) * K + kn + c8 + 4];
        __syncthreads();

#pragma unroll
        for (int kc = 0; kc < 2; ++kc) {
            bf16x8 af[2], bfr[2];
            af[0]  = *(const bf16x8*)&As[wm + lrow][kc * 32 + 8 * quad];
            af[1]  = *(const bf16x8*)&As[wm + 16 + lrow][kc * 32 + 8 * quad];
            bfr[0] = *(const bf16x8*)&Bs[wn + lrow][kc * 32 + 8 * quad];
            bfr[1] = *(const bf16x8*)&Bs[wn + 16 + lrow][kc * 32 + 8 * quad];
#pragma unroll
            for (int t = 0; t < 2; ++t)
#pragma unroll
                for (int u = 0; u < 2; ++u)
                    acc[t][u] = __builtin_amdgcn_mfma_f32_16x16x32_bf16(
                        af[t], bfr[u], acc[t][u], 0, 0, 0);
        }
        __syncthreads();
    }

#pragma unroll
    for (int t = 0; t < 2; ++t) {
#pragma unroll
        for (int u = 0; u < 2; ++u) {
            const int col = n0 + wn + u * 16 + lrow;
            const float bvv = bias[col];
#pragma unroll
            for (int r = 0; r < 4; ++r) {
                const int row = m0 + wm + t * 16 + quad * 4 + r;
                outF[(size_t)row * D_ + col] = acc[t][u][r] + bvv;
            }
        }
    }
}

// ---------------------------------------------------------------------------
// MFMA flash attention, r29: pre-skewed band + bias-folded init + DEAD-
// GROUP ELISION. Live skT read rows are [31,94] only (jj+31, jj in [0,63]).
// Store-group (up,m) spans rows [16(up+m), 16(up+m)+30]:
//   (up=0,m=0) -> rows [0,30]   : entirely dead (jj<0 never consumed)
//   (up=5,m=1) -> rows [96,126] : entirely dead (jj>63)
// Both conditions are compile-time uniform (unroll constants) -> elide 4
// of 24 rel MFMAs and 8 of 48 skew-writes per iteration, zero divergence.
// E loads stay (each up feeds one live m).
// Everything else identical to the measured-best config: fixed-shift
// softmax with bias in accumulator init, skT stride 36, vector bf16x4
// skew reads, XCD-localized swizzle, setprio on PV, rolled t-loop.
// ---------------------------------------------------------------------------
__global__ __launch_bounds__(256) void fattn_kernel(
    const bf16_t* __restrict__ qbh, const bf16_t* __restrict__ kbh,
    const bf16_t* __restrict__ vtb, const bf16_t* __restrict__ Eb,
    bf16_t* __restrict__ ctx) {
    // loop phase : skT[w] = [127][36] bf16 @ w*9216 B (4572 el < 4608);
    //              P tile reuses skT[w] with stride 72 (2304 el < 4608)
    // merge phase: Om[4][32][64] f32 @ 0 | ml[4][32] f32 @ 32768
    __shared__ __align__(16) char smem[36864];
    float (*Om)[32][64] = (float(*)[32][64])smem;
    float (*ml)[32]     = (float(*)[32])(smem + 32768);

    const int tid = threadIdx.x;
    const int w = tid >> 6;
    const int lane = tid & 63;
    const int q4 = lane >> 4;
    const int n = lane & 15;

    // XCD-localized decode: xcd = bid&7 owns bh in [4*xcd, 4*xcd+4)
    const int bid = blockIdx.x;
    const int xcd = bid & 7;
    const int k = bid >> 3;              // 0..127 within XCD
    const int bh = (xcd << 2) | (k >> 5);
    const int b = bh >> 4;
    const int h = bh & 15;
    const int ib = (k & 31) << 5;

    bf16_t* skT = (bf16_t*)smem + (size_t)w * 4608;
    bf16_t* ps = skT;   // aliased: skT dead after skew-add, P stride 72

    // ones B-fragment for the MFMA row-sum trick
    bf16x8 ones;
#pragma unroll
    for (int e = 0; e < 8; ++e) ones[e] = (bf16_t)1.0f;

    bf16x8 aq[2][2];
#pragma unroll
    for (int m = 0; m < 2; ++m) {
        const bf16x8* qrow =
            (const bf16x8*)(qbh + ((size_t)bh * L_ + ib + 16 * m + n) * HD_);
        aq[m][0] = qrow[q4];
        aq[m][1] = qrow[4 + q4];
    }

    const bf16_t* vbase = vtb + (size_t)bh * HD_ * L_;

    f32x4 o[2][4] = {};
    float l_r[2][4] = {};

    for (int t = 0; t < 4; ++t) {
        const int j0 = w * 256 + t * 64;

        // ---- prefetch K fragments ----
        bf16x8 bk[4][2];
#pragma unroll
        for (int u = 0; u < 4; ++u)
#pragma unroll
            for (int kc = 0; kc < 2; ++kc)
                bk[u][kc] = *(const bf16x8*)(kbh +
                    ((size_t)bh * L_ + j0 + 16 * u + n) * HD_ + kc * 32 + 8 * q4);

        // ---- rel: R = Q @ Eband^T, stored PRE-SKEWED skT[p'+qrow][qrow];
        //      groups (up+m)==0 and (up+m)==6 elided (rows never read) ----
        const int rbase = j0 - ib + 992;   // Eb row = rbase + p', p' in [0,96)
#pragma unroll
        for (int up = 0; up < 6; ++up) {
            f32x4 rc[2] = {};
#pragma unroll
            for (int kc = 0; kc < 2; ++kc) {
                const bf16x8 be = *(const bf16x8*)(Eb +
                    ((size_t)(rbase + 16 * up + n)) * HD_ + kc * 32 + 8 * q4);
#pragma unroll
                for (int m = 0; m < 2; ++m) {
                    if (up + m == 0 || up + m == 6) continue;  // dead group
                    rc[m] = __builtin_amdgcn_mfma_f32_16x16x32_bf16(
                        aq[m][kc], be, rc[m], 0, 0, 0);
                }
            }
            // rc[m][r] = q_{16m+4q4+r} . E_{rbase + 16up + n}
            // store row = p' + qrow = 16(up+m) + n + 4q4 + r, col = qrow
#pragma unroll
            for (int m = 0; m < 2; ++m) {
                if (up + m == 0 || up + m == 6) continue;      // dead group
                const int base =
                    (16 * (up + m) + n + 4 * q4) * 36 + 16 * m + 4 * q4;
#pragma unroll
                for (int r = 0; r < 4; ++r)
                    skT[base + 37 * r] = (bf16_t)rc[m][r];
            }
        }

        // ---- S = Q K^T - 24 (bias folded into accumulator init) ----
        f32x4 s[2][4];
#pragma unroll
        for (int m = 0; m < 2; ++m)
#pragma unroll
            for (int u = 0; u < 4; ++u)
#pragma unroll
                for (int r = 0; r < 4; ++r)
                    s[m][u][r] = -24.0f;
#pragma unroll
        for (int u = 0; u < 4; ++u)
#pragma unroll
            for (int kc = 0; kc < 2; ++kc)
#pragma unroll
                for (int m = 0; m < 2; ++m)
                    s[m][u] = __builtin_amdgcn_mfma_f32_16x16x32_bf16(
                        aq[m][kc], bk[u][kc], s[m][u], 0, 0, 0);

        // ---- prefetch V fragments ----
        bf16x8 vf[4][2];
#pragma unroll
        for (int u = 0; u < 4; ++u)
#pragma unroll
            for (int kc = 0; kc < 2; ++kc)
                vf[u][kc] = *(const bf16x8*)(vbase +
                    ((size_t)(16 * u + n)) * L_ + j0 + kc * 32 + 8 * q4);

        // ---- skew add (vector) + fixed-shift exp2: P = 2^(S + sk) ----
#pragma unroll
        for (int m = 0; m < 2; ++m)
#pragma unroll
            for (int u = 0; u < 4; ++u) {
                const bf16x4 sk = *(const bf16x4*)&skT[
                    (size_t)(16 * u + n + 31) * 36 + 16 * m + 4 * q4];
#pragma unroll
                for (int r = 0; r < 4; ++r)
                    s[m][u][r] = __builtin_amdgcn_exp2f(
                        s[m][u][r] + (float)sk[r]);
            }

        // ---- P -> LDS (stride 72), then A-frags ----
#pragma unroll
        for (int m = 0; m < 2; ++m)
#pragma unroll
            for (int u = 0; u < 4; ++u)
#pragma unroll
                for (int r = 0; r < 4; ++r)
                    ps[(size_t)(16 * m + 4 * q4 + r) * 72 + 16 * u + n] =
                        (bf16_t)s[m][u][r];

        bf16x8 pa[2][2];
#pragma unroll
        for (int m = 0; m < 2; ++m) {
            pa[m][0] = *(const bf16x8*)&ps[(size_t)(16 * m + n) * 72 + 8 * q4];
            pa[m][1] = *(const bf16x8*)&ps[(size_t)(16 * m + n) * 72 + 32 + 8 * q4];
        }

        // ---- row-sum via MFMA P @ ones (no rescale needed) ----
#pragma unroll
        for (int m = 0; m < 2; ++m) {
            f32x4 z = {};
            z = __builtin_amdgcn_mfma_f32_16x16x32_bf16(pa[m][0], ones, z, 0, 0, 0);
            z = __builtin_amdgcn_mfma_f32_16x16x32_bf16(pa[m][1], ones, z, 0, 0, 0);
#pragma unroll
            for (int r = 0; r < 4; ++r)
                l_r[m][r] += z[r];
        }

        // ---- O += P V (pure-MFMA cluster; setprio breaks wave lockstep) ----
        __builtin_amdgcn_s_setprio(1);
#pragma unroll
        for (int u = 0; u < 4; ++u)
#pragma unroll
            for (int kc = 0; kc < 2; ++kc)
#pragma unroll
                for (int m = 0; m < 2; ++m)
                    o[m][u] = __builtin_amdgcn_mfma_f32_16x16x32_bf16(
                        pa[m][kc], vf[u][kc], o[m][u], 0, 0, 0);
        __builtin_amdgcn_s_setprio(0);
    }

    // ---- 4-way cross-wave merge (sum-only: no max bookkeeping) ----
    __syncthreads();
#pragma unroll
    for (int m = 0; m < 2; ++m)
#pragma unroll
        for (int u = 0; u < 4; ++u)
#pragma unroll
            for (int r = 0; r < 4; ++r)
                Om[w][16 * m + 4 * q4 + r][16 * u + n] = o[m][u][r];
    if (n == 0) {
#pragma unroll
        for (int m = 0; m < 2; ++m)
#pragma unroll
            for (int r = 0; r < 4; ++r)
                ml[w][16 * m + 4 * q4 + r] = l_r[m][r];
    }
    __syncthreads();

    {
        const int row = tid >> 3;          // 0..31
        const int c0 = (tid & 7) * 8;      // 0..56
        const float inv = 1.f / (ml[0][row] + ml[1][row] +
                                 ml[2][row] + ml[3][row]);
        bf16_t* dst = ctx + ((size_t)(b * L_ + ib + row)) * D_ + h * HD_ + c0;
#pragma unroll
        for (int cc = 0; cc < 8; ++cc) {
            const int col = c0 + cc;
            const float val = (Om[0][row][col] + Om[1][row][col] +
                               Om[2][row][col] + Om[3][row][col]) * inv;
            dst[cc] = (bf16_t)val;
        }
    }
}

// ---------------------------------------------------------------------------
extern "C" void kernel_launch(void* const* d_in, const int* in_sizes, int n_in,
                              void* d_out, int out_size, void* d_ws,
                              size_t ws_size, hipStream_t stream) {
    const float* x   = (const float*)d_in[0];
    const float* Wq  = (const float*)d_in[1];
    const float* bq  = (const float*)d_in[2];
    const float* Wk  = (const float*)d_in[3];
    const float* bk  = (const float*)d_in[4];
    const float* Wv  = (const float*)d_in[5];
    const float* bv  = (const float*)d_in[6];
    const float* Wo  = (const float*)d_in[7];
    const float* bo  = (const float*)d_in[8];
    const float* E   = (const float*)d_in[9];
    float* out = (float*)d_out;   // fp32 per reference

    char* ws = (char*)d_ws;
    const size_t MB = 1024u * 1024u;
    bf16_t* xb   = (bf16_t*)(ws);             // 4 MB
    bf16_t* qbh  = (bf16_t*)(ws + 4 * MB);    // 4 MB (BH,L,64), pre-scaled
    bf16_t* kbh  = (bf16_t*)(ws + 8 * MB);    // 4 MB (BH,L,64)
    bf16_t* vtb  = (bf16_t*)(ws + 12 * MB);   // 4 MB (BH,64,L) transposed
    bf16_t* ctxb = (bf16_t*)(ws + 16 * MB);   // 4 MB (B,L,D)
    bf16_t* Eb   = (bf16_t*)(ws + 20 * MB);   // 0.25 MB (2048x64)

    prep_kernel<<<2560, 256, 0, stream>>>(x, E, xb, Eb);

    dim3 gq(D_ / 64, (B_ * L_) / 64, 3);  // 1536 blocks
    qkv_gemm_kernel<<<gq, 256, 0, stream>>>(xb, Wq, Wk, Wv, bq, bk, bv,
                                            qbh, kbh, vtb);

    fattn_kernel<<<1024, 256, 0, stream>>>(qbh, kbh, vtb, Eb, ctxb);

    dim3 gg(D_ / 64, (B_ * L_) / 64);  // 512 blocks
    out_gemm_kernel<<<gg, 256, 0, stream>>>(ctxb, Wo, bo, out);
}